// Round 2
// baseline (46346.967 us; speedup 1.0000x reference)
//
#include <hip/hip_runtime.h>
#include <hip/hip_bf16.h>

// ---------------------------------------------------------------------------
// Gated-RNN (minimal GRU variant) fused persistent kernel for MI355X (gfx950).
//
//   xp = x@wp + bp ; xh = x@wh + bh            (fused into the step, K=256)
//   p  = sigmoid(xp_t + h@up + p_prev@gp)
//   h~ = tanh   (xh_t + h@uh)
//   h  = (1-p)*p_prev_state... no: h = (1-p)*h_prev + p*h~
//
// Decomposition: 8 batch-groups (8 batches) x 32 column-wgs (16 cols) = 256 wgs.
// Weights live in registers as split-bf16 (hi+lo) MFMA fragments; 3-term
// hi*hi + hi*lo + lo*hi MFMA products give ~fp32 accuracy (~1e-5 rel).
// Per-step cross-wg sync: one monotonic per-group counter (agent-scope
// atomicAdd, release); state ping-pongs in workspace as bf16 hi/lo pairs.
// rnn_seq is launched cooperatively -> co-residency of all 256 wgs is
// GUARANTEED (a plain launch can hang the spin-wait if any wg is deferred).
// ---------------------------------------------------------------------------

typedef short bf16x8 __attribute__((ext_vector_type(8)));
typedef float f32x4  __attribute__((ext_vector_type(4)));
typedef unsigned short u16;

#define MFMA16(a, b, c) __builtin_amdgcn_mfma_f32_16x16x32_bf16((a), (b), (c), 0, 0, 0)

constexpr int Bsz = 64, Tsz = 1024, Dsz = 256, Hsz = 512;
constexpr int NGRP   = 8;              // batch groups (-> XCDs)
constexpr int NB     = 8;              // batches per group
constexpr int NCW    = 32;             // column-wgs per group
constexpr int CW     = 16;             // columns per wg
constexpr int NWAVES = 4;
constexpr int RKS = Hsz / 32;          // 16 recurrent K-steps
constexpr int RKW = RKS / NWAVES;      // 4 per wave
constexpr int PKS = Dsz / 32;          // 8 projection K-steps
constexpr int PKW = PKS / NWAVES;      // 2 per wave

__device__ __forceinline__ u16 f2bf(float f) {
  unsigned u = __float_as_uint(f);
  u = (u + 0x7fffu + ((u >> 16) & 1u)) >> 16;   // RNE
  return (u16)u;
}
__device__ __forceinline__ float bf2f(u16 s) {
  return __uint_as_float(((unsigned)s) << 16);
}
// state buffer layout: [parity][group][arr: h_hi,h_lo,p_hi,p_lo][b][k]
__device__ __forceinline__ size_t sidx(int par, int grp, int arr, int b, int k) {
  return ((((size_t)((par * NGRP + grp) * 4 + arr)) * NB + b) * Hsz + k);
}

__global__ void rnn_init(const float* __restrict__ p0, const float* __restrict__ h0,
                         unsigned* __restrict__ flags, u16* __restrict__ sbuf) {
  const int idx = blockIdx.x * blockDim.x + threadIdx.x;   // 0..32767
  if (idx < 4096) flags[idx] = 0;                          // zero counters (+pad)
  const int b = idx >> 9;                                  // 0..63
  const int k = idx & (Hsz - 1);
  const int grp = b >> 3, lb = b & 7;
  const float hv = h0[(size_t)b * Hsz + k];
  const float pv = p0[(size_t)b * Hsz + k];
  const u16 hh = f2bf(hv), hl = f2bf(hv - bf2f(hh));
  const u16 ph = f2bf(pv), pl = f2bf(pv - bf2f(ph));
  const size_t o = sidx(0, grp, 0, lb, k);
  sbuf[o]                        = hh;
  sbuf[o + (size_t)1 * NB * Hsz] = hl;
  sbuf[o + (size_t)2 * NB * Hsz] = ph;
  sbuf[o + (size_t)3 * NB * Hsz] = pl;
}

__global__ __launch_bounds__(256, 1) void rnn_seq(
    const float* __restrict__ x,
    const float* __restrict__ up, const float* __restrict__ gp,
    const float* __restrict__ uh,
    const float* __restrict__ wp, const float* __restrict__ wh,
    const float* __restrict__ bp, const float* __restrict__ bh,
    const float* __restrict__ h0,
    float* __restrict__ out,
    unsigned* __restrict__ flags, u16* __restrict__ sbuf) {
  const int wg    = blockIdx.x;
  const int grp   = wg & (NGRP - 1);   // group == blockIdx%8 -> same XCD (heuristic)
  const int cw    = wg >> 3;           // 0..31 column-wg
  const int cbase = cw * CW;
  const int tid   = threadIdx.x;
  const int wave  = tid >> 6;
  const int lane  = tid & 63;
  const int frow  = lane & 15;         // fragment row (batch) / B-frag col
  const int fkc   = lane >> 4;         // k-chunk 0..3
  const int bA    = frow & (NB - 1);   // rows 8..15 -> duplicate batches

  __shared__ float part[NWAVES][2][NB][CW];   // per-wave partial sums (a,c)
  __shared__ float h_old[NB][CW];             // our slice of h state (fp32)

  // ---- startup: load all weight B-fragments into registers (hi/lo bf16) ----
  const int col = cbase + frow;
  bf16x8 Uh[RKW], Ul[RKW], Gh[RKW], Gl[RKW], Vh[RKW], Vl[RKW];
#pragma unroll
  for (int i = 0; i < RKW; ++i) {
    const int kb = (wave * RKW + i) * 32 + fkc * 8;
    const float* pu = up + (size_t)kb * Hsz + col;
    const float* pg = gp + (size_t)kb * Hsz + col;
    const float* pv = uh + (size_t)kb * Hsz + col;
#pragma unroll
    for (int e = 0; e < 8; ++e) {
      float w0 = pu[(size_t)e * Hsz]; u16 a_ = f2bf(w0);
      Uh[i][e] = (short)a_; Ul[i][e] = (short)f2bf(w0 - bf2f(a_));
      float w1 = pg[(size_t)e * Hsz]; u16 b_ = f2bf(w1);
      Gh[i][e] = (short)b_; Gl[i][e] = (short)f2bf(w1 - bf2f(b_));
      float w2 = pv[(size_t)e * Hsz]; u16 c_ = f2bf(w2);
      Vh[i][e] = (short)c_; Vl[i][e] = (short)f2bf(w2 - bf2f(c_));
    }
  }
  bf16x8 Ph[PKW], Pl[PKW], Qh[PKW], Ql[PKW];   // wp, wh fragments
#pragma unroll
  for (int i = 0; i < PKW; ++i) {
    const int kb = (wave * PKW + i) * 32 + fkc * 8;
    const float* pp = wp + (size_t)kb * Hsz + col;
    const float* pq = wh + (size_t)kb * Hsz + col;
#pragma unroll
    for (int e = 0; e < 8; ++e) {
      float w0 = pp[(size_t)e * Hsz]; u16 a_ = f2bf(w0);
      Ph[i][e] = (short)a_; Pl[i][e] = (short)f2bf(w0 - bf2f(a_));
      float w1 = pq[(size_t)e * Hsz]; u16 b_ = f2bf(w1);
      Qh[i][e] = (short)b_; Ql[i][e] = (short)f2bf(w1 - bf2f(b_));
    }
  }

  // ---- epilogue-thread setup (threads 0..127 own one (b, j) output each) ----
  const int eb = tid >> 4, ej = tid & 15;
  float bpv = 0.f, bhv = 0.f;
  if (tid < NB * CW) {
    bpv = bp[cbase + ej];
    bhv = bh[cbase + ej];
    h_old[eb][ej] = h0[(size_t)(grp * NB + eb) * Hsz + cbase + ej];
  }

  // ---- x prefetch for t = 0 ----
  const float* xrow = x + (size_t)(grp * NB + bA) * Tsz * Dsz;
  f32x4 xc[2 * PKW];
#pragma unroll
  for (int i = 0; i < PKW; ++i) {
    const float* px = xrow + (wave * PKW + i) * 32 + fkc * 8;
    xc[2 * i]     = *(const f32x4*)px;
    xc[2 * i + 1] = *(const f32x4*)(px + 4);
  }

  // one monotonic counter per group, 64 B apart
  unsigned* ctr = flags + (size_t)grp * 16;

  for (int t = 0; t < Tsz; ++t) {
    // -- 1. wait for the whole group's step t-1 state --
    if (t > 0) {
      if (tid == 0) {
        while (__hip_atomic_load(ctr, __ATOMIC_RELAXED, __HIP_MEMORY_SCOPE_AGENT) <
               (unsigned)(NCW * t)) {
          __builtin_amdgcn_s_sleep(1);
        }
      }
      __syncthreads();
      __threadfence();   // acquire: make remote state stores visible
    }

    // -- 2. x fragments for this step; prefetch t+1 --
    bf16x8 Xh[PKW], Xl[PKW];
#pragma unroll
    for (int i = 0; i < PKW; ++i) {
#pragma unroll
      for (int e = 0; e < 8; ++e) {
        float v = (e < 4) ? xc[2 * i][e] : xc[2 * i + 1][e - 4];
        u16 a_ = f2bf(v);
        Xh[i][e] = (short)a_;
        Xl[i][e] = (short)f2bf(v - bf2f(a_));
      }
    }
    {
      const int tn = (t + 1 < Tsz) ? t + 1 : Tsz - 1;
#pragma unroll
      for (int i = 0; i < PKW; ++i) {
        const float* px = xrow + (size_t)tn * Dsz + (wave * PKW + i) * 32 + fkc * 8;
        xc[2 * i]     = *(const f32x4*)px;
        xc[2 * i + 1] = *(const f32x4*)(px + 4);
      }
    }

    // -- 3. matmuls: a = h@up + p@gp + x@wp ; c = h@uh + x@wh (split-bf16) --
    f32x4 A0 = {0,0,0,0}, A1 = {0,0,0,0}, A2 = {0,0,0,0};
    f32x4 C0 = {0,0,0,0}, C1 = {0,0,0,0}, C2 = {0,0,0,0};
    const u16* sb = sbuf + sidx(t & 1, grp, 0, bA, 0);
#pragma unroll
    for (int i = 0; i < RKW; ++i) {
      const int ko = (wave * RKW + i) * 32 + fkc * 8;
      bf16x8 hh = *(const bf16x8*)(sb + ko);
      bf16x8 hl = *(const bf16x8*)(sb + (size_t)1 * NB * Hsz + ko);
      bf16x8 ph = *(const bf16x8*)(sb + (size_t)2 * NB * Hsz + ko);
      bf16x8 pl = *(const bf16x8*)(sb + (size_t)3 * NB * Hsz + ko);
      A0 = MFMA16(hh, Uh[i], A0);
      A1 = MFMA16(hh, Ul[i], A1);
      A2 = MFMA16(hl, Uh[i], A2);
      A0 = MFMA16(ph, Gh[i], A0);
      A1 = MFMA16(ph, Gl[i], A1);
      A2 = MFMA16(pl, Gh[i], A2);
      C0 = MFMA16(hh, Vh[i], C0);
      C1 = MFMA16(hh, Vl[i], C1);
      C2 = MFMA16(hl, Vh[i], C2);
    }
#pragma unroll
    for (int i = 0; i < PKW; ++i) {
      A0 = MFMA16(Xh[i], Ph[i], A0);
      A1 = MFMA16(Xh[i], Pl[i], A1);
      A2 = MFMA16(Xl[i], Ph[i], A2);
      C0 = MFMA16(Xh[i], Qh[i], C0);
      C1 = MFMA16(Xh[i], Ql[i], C1);
      C2 = MFMA16(Xl[i], Qh[i], C2);
    }

    // -- 4. dump per-wave partials (C rows 0..7 live in lanes 0..31) --
    if (lane < 32) {
      const int pc = lane & 15, pr = (lane >> 4) * 4;
#pragma unroll
      for (int r = 0; r < 4; ++r) {
        part[wave][0][pr + r][pc] = A0[r] + A1[r] + A2[r];
        part[wave][1][pr + r][pc] = C0[r] + C1[r] + C2[r];
      }
    }
    __syncthreads();

    // -- 5. reduce + gate + publish state --
    if (tid < NB * CW) {
      float a = bpv, c = bhv;
#pragma unroll
      for (int w = 0; w < NWAVES; ++w) {
        a += part[w][0][eb][ej];
        c += part[w][1][eb][ej];
      }
      const float pnew  = 1.f / (1.f + __expf(-a));
      const float e2    = __expf(2.f * c);
      const float th    = 1.f - 2.f / (e2 + 1.f);
      const float hprev = h_old[eb][ej];
      const float hnew  = (1.f - pnew) * hprev + pnew * th;
      h_old[eb][ej] = hnew;
      out[((size_t)(grp * NB + eb) * Tsz + t) * Hsz + cbase + ej] = hnew;
      const u16 hh_ = f2bf(hnew);
      const u16 hl_ = f2bf(hnew - bf2f(hh_));
      const u16 ph_ = f2bf(pnew);
      const u16 pl_ = f2bf(pnew - bf2f(ph_));
      const size_t o = sidx((t + 1) & 1, grp, 0, eb, cbase + ej);
      sbuf[o]                        = hh_;
      sbuf[o + (size_t)1 * NB * Hsz] = hl_;
      sbuf[o + (size_t)2 * NB * Hsz] = ph_;
      sbuf[o + (size_t)3 * NB * Hsz] = pl_;
    }

    // -- 6. release + bump group counter --
    __threadfence();
    __syncthreads();
    if (tid == 0)
      __hip_atomic_fetch_add(ctr, 1u, __ATOMIC_RELEASE, __HIP_MEMORY_SCOPE_AGENT);
  }
}

extern "C" void kernel_launch(void* const* d_in, const int* in_sizes, int n_in,
                              void* d_out, int out_size, void* d_ws, size_t ws_size,
                              hipStream_t stream) {
  (void)in_sizes; (void)n_in; (void)out_size; (void)ws_size;
  const float* x  = (const float*)d_in[0];
  const float* wh = (const float*)d_in[1];
  const float* uh = (const float*)d_in[2];
  const float* bh = (const float*)d_in[3];
  const float* wp = (const float*)d_in[4];
  const float* up = (const float*)d_in[5];
  const float* gp = (const float*)d_in[6];
  const float* bp = (const float*)d_in[7];
  const float* p0 = (const float*)d_in[8];
  const float* h0 = (const float*)d_in[9];
  float* out = (float*)d_out;

  unsigned* flags = (unsigned*)d_ws;                    // 16 KB used (64 KB reserved)
  u16*      sbuf  = (u16*)((char*)d_ws + 64 * 1024);    // 512 KB state ping-pong

  rnn_init<<<dim3(128), dim3(256), 0, stream>>>(p0, h0, flags, sbuf);

  void* args[] = {(void*)&x,  (void*)&up, (void*)&gp, (void*)&uh,
                  (void*)&wp, (void*)&wh, (void*)&bp, (void*)&bh,
                  (void*)&h0, (void*)&out, (void*)&flags, (void*)&sbuf};
  hipError_t e = hipLaunchCooperativeKernel((void*)rnn_seq, dim3(NGRP * NCW),
                                            dim3(256), args, 0, stream);
  if (e != hipSuccess) {
    // co-residency not granted via cooperative path: fall back (256 wgs on
    // 256 CUs at 1 block/CU will in practice all be resident)
    rnn_seq<<<dim3(NGRP * NCW), dim3(256), 0, stream>>>(
        x, up, gp, uh, wp, wh, bp, bh, h0, out, flags, sbuf);
  }
}